// Round 3
// baseline (329.728 us; speedup 1.0000x reference)
//
#include <hip/hip_runtime.h>

// LeakyZOPlainOnce: 32-step LIF scan with LocalZO straight-through surrogate.
// inputs:  d_in[0] = x  (T*B*F fp32), d_in[1] = z (same shape)
// output:  d_out    = spikes (T*B*F fp32)
//
// R3 theory: R0 and R2 both had exactly 32 KB/CU of loads in flight
// (16 waves x 2KB vs 32 waves x 1KB) and both ran ~3-3.6 TB/s app-side ->
// MLP-starved, not BW-bound. This round: VEC=4 + explicit 3-deep software
// pipeline (ring of 4 float4 buffers, prefetch distance 3, unroll 4 so ring
// indices are constants) -> 6 KB/wave, 96 KB/CU in flight. Plain stores
// (nt store reverted to isolate variables).
//
// Determinism: spike = (h - surr*v) + surr*v is NOT exactly h when
// surr*v > 2; residual feeds the u recurrence, so fp32 op order must match
// numpy exactly. R2's absmax 4.5e-07 was FMA contraction inside lif_step
// (pragma in kernel body doesn't cover the callee) -> pragma moved INSIDE.

constexpr int BATCH = 128;
constexpr int FDIM  = 8192;
constexpr int STEP  = BATCH * FDIM;   // elements per time step = 1,048,576
constexpr int VEC   = 4;              // floats per thread per step

__device__ __forceinline__ float lif_step(float& u, float xs, float zs)
{
#pragma clang fp contract(off)
    float uu = 0.5f * u;          // beta * u   (separate mul + add)
    uu = uu + xs;
    float v = uu - 1.0f;          // u - u_th
    float az   = fabsf(zs);
    float ind  = (fabsf(v) < 0.05f * az) ? 1.0f : 0.0f;
    float surr = (az / 0.1f) * ind;
    float h    = (v > 0.0f) ? 1.0f : 0.0f;
    float a     = surr * v;
    float spike = (h - a) + a;    // straight-through forward
    u = uu - spike * 1.0f;        // soft reset
    return spike;
}

__global__ __launch_bounds__(256) void lif_zo_kernel(
    const float* __restrict__ x,
    const float* __restrict__ z,
    float* __restrict__ out,
    int T)
{
#pragma clang fp contract(off)
    const int tid = blockIdx.x * blockDim.x + threadIdx.x;
    const long base = (long)tid * VEC;

    float u[VEC] = {0.0f, 0.0f, 0.0f, 0.0f};
    float4 xb[4], zb[4];

    // preload t = 0,1,2 (clamped for tiny T; T=32 here)
#pragma unroll
    for (int k = 0; k < 3; ++k) {
        const int tk = (k < T) ? k : (T - 1);
        const long a = base + (long)tk * STEP;
        xb[k] = *reinterpret_cast<const float4*>(x + a);
        zb[k] = *reinterpret_cast<const float4*>(z + a);
    }

    long widx = base;
#pragma unroll 4
    for (int t = 0; t < T; ++t) {
        // prefetch t+3 into ring slot (t+3)&3 (slot was consumed at t-1)
        long p = widx + 3L * (long)STEP;
        if (t + 3 >= T) p = widx;     // harmless tail reload
        xb[(t + 3) & 3] = *reinterpret_cast<const float4*>(x + p);
        zb[(t + 3) & 3] = *reinterpret_cast<const float4*>(z + p);

        const float4 xt = xb[t & 3];
        const float4 zt = zb[t & 3];
        float4 s;
        s.x = lif_step(u[0], xt.x, zt.x);
        s.y = lif_step(u[1], xt.y, zt.y);
        s.z = lif_step(u[2], xt.z, zt.z);
        s.w = lif_step(u[3], xt.w, zt.w);

        *reinterpret_cast<float4*>(out + widx) = s;
        widx += STEP;
    }
}

extern "C" void kernel_launch(void* const* d_in, const int* in_sizes, int n_in,
                              void* d_out, int out_size, void* d_ws, size_t ws_size,
                              hipStream_t stream)
{
    const float* x = (const float*)d_in[0];
    const float* z = (const float*)d_in[1];
    float* out = (float*)d_out;

    const int total = in_sizes[0];          // T * B * F
    const int T = total / STEP;             // = 32 for this problem

    const int nthreads = STEP / VEC;        // 262,144
    const int block = 256;
    const int grid = nthreads / block;      // 1024

    lif_zo_kernel<<<grid, block, 0, stream>>>(x, z, out, T);
}

// Round 5
// 325.500 us; speedup vs baseline: 1.0130x; 1.0130x over previous
//
#include <hip/hip_runtime.h>

// LeakyZOPlainOnce: 32-step LIF scan with LocalZO straight-through surrogate.
// inputs:  d_in[0] = x  (T*B*F fp32), d_in[1] = z (same shape)
// output:  d_out    = spikes (T*B*F fp32)
//
// R5 = R4 with the compile fix: __builtin_nontemporal_store requires a
// clang native vector (ext_vector_type), not HIP's float4 class type.
//
// Structure rationale:
//  - R3's ring buffer was demoted to LDS+scratch (LDS_Block_Size=16384,
//    5M bank conflicts, WRITE_SIZE doubled by spill traffic) because the
//    partial unroll left (t+3)&3 runtime-valued. Fix: T as template param,
//    FULL unroll -> all ring indices are literals -> SROA -> VGPRs.
//  - VEC=4 (R2 showed VEC=2's 2x instruction overhead beats its occupancy
//    gain), 3-deep prefetch: 6 KB loads in flight per wave, ~96 KB/CU.
//  - nontemporal stores: inputs (268 MB) exactly fill the 256 MiB LLC and
//    are LLC-warm from the harness restore; R0's FETCH=134 MB == half the
//    inputs shows write-allocation evicted them. nt keeps the output
//    stream out of LLC.
//
// Determinism: spike = (h - surr*v) + surr*v is NOT exactly h when
// surr*v > 2; the residual feeds the u recurrence, so fp32 op order must
// match numpy exactly: separate mul+add with fp contract OFF inside
// lif_step (R2's absmax 4.5e-7 was FMA contraction sneaking into the
// inlined callee), true IEEE division by 0.1f, strict comparisons.

constexpr int BATCH = 128;
constexpr int FDIM  = 8192;
constexpr int STEP  = BATCH * FDIM;   // elements per time step = 1,048,576
constexpr int VEC   = 4;              // floats per thread per step
constexpr int PFD   = 3;              // prefetch distance (ring of 4)

typedef float f32x4 __attribute__((ext_vector_type(4)));

__device__ __forceinline__ float lif_step(float& u, float xs, float zs)
{
#pragma clang fp contract(off)
    float uu = 0.5f * u;          // beta * u   (separate mul + add)
    uu = uu + xs;
    float v = uu - 1.0f;          // u - u_th
    float az   = fabsf(zs);
    float ind  = (fabsf(v) < 0.05f * az) ? 1.0f : 0.0f;
    float surr = (az / 0.1f) * ind;
    float h    = (v > 0.0f) ? 1.0f : 0.0f;
    float a     = surr * v;
    float spike = (h - a) + a;    // straight-through forward
    u = uu - spike * 1.0f;        // soft reset
    return spike;
}

template <int T>
__global__ __launch_bounds__(256) void lif_zo_fixed(
    const float* __restrict__ x,
    const float* __restrict__ z,
    float* __restrict__ out)
{
#pragma clang fp contract(off)
    const int tid = blockIdx.x * blockDim.x + threadIdx.x;
    const long base = (long)tid * VEC;

    float u[VEC] = {0.0f, 0.0f, 0.0f, 0.0f};
    f32x4 xb[PFD + 1], zb[PFD + 1];

    // preload t = 0..PFD-1 (T > PFD for all uses of this template)
#pragma unroll
    for (int k = 0; k < PFD; ++k) {
        const long a = base + (long)k * STEP;
        xb[k] = *reinterpret_cast<const f32x4*>(x + a);
        zb[k] = *reinterpret_cast<const f32x4*>(z + a);
    }

#pragma unroll
    for (int t = 0; t < T; ++t) {
        if (t + PFD < T) {   // compile-time under full unroll
            const long p = base + (long)(t + PFD) * STEP;
            xb[(t + PFD) & 3] = *reinterpret_cast<const f32x4*>(x + p);
            zb[(t + PFD) & 3] = *reinterpret_cast<const f32x4*>(z + p);
        }
        const f32x4 xt = xb[t & 3];
        const f32x4 zt = zb[t & 3];
        f32x4 s;
        s.x = lif_step(u[0], xt.x, zt.x);
        s.y = lif_step(u[1], xt.y, zt.y);
        s.z = lif_step(u[2], xt.z, zt.z);
        s.w = lif_step(u[3], xt.w, zt.w);
        __builtin_nontemporal_store(
            s, reinterpret_cast<f32x4*>(out + base + (long)t * STEP));
    }
}

// Generic-T fallback (R0 structure: proven correct, no arrays).
__global__ __launch_bounds__(256) void lif_zo_generic(
    const float* __restrict__ x,
    const float* __restrict__ z,
    float* __restrict__ out,
    int T)
{
#pragma clang fp contract(off)
    const int tid = blockIdx.x * blockDim.x + threadIdx.x;
    long idx = (long)tid * VEC;
    float u[VEC] = {0.0f, 0.0f, 0.0f, 0.0f};
    for (int t = 0; t < T; ++t, idx += STEP) {
        const f32x4 xt = *reinterpret_cast<const f32x4*>(x + idx);
        const f32x4 zt = *reinterpret_cast<const f32x4*>(z + idx);
        f32x4 s;
        s.x = lif_step(u[0], xt.x, zt.x);
        s.y = lif_step(u[1], xt.y, zt.y);
        s.z = lif_step(u[2], xt.z, zt.z);
        s.w = lif_step(u[3], xt.w, zt.w);
        *reinterpret_cast<f32x4*>(out + idx) = s;
    }
}

extern "C" void kernel_launch(void* const* d_in, const int* in_sizes, int n_in,
                              void* d_out, int out_size, void* d_ws, size_t ws_size,
                              hipStream_t stream)
{
    const float* x = (const float*)d_in[0];
    const float* z = (const float*)d_in[1];
    float* out = (float*)d_out;

    const int total = in_sizes[0];          // T * B * F
    const int T = total / STEP;             // = 32 for this problem

    const int nthreads = STEP / VEC;        // 262,144
    const int block = 256;
    const int grid = nthreads / block;      // 1024

    if (T == 32) {
        lif_zo_fixed<32><<<grid, block, 0, stream>>>(x, z, out);
    } else {
        lif_zo_generic<<<grid, block, 0, stream>>>(x, z, out, T);
    }
}

// Round 6
// 314.372 us; speedup vs baseline: 1.0488x; 1.0354x over previous
//
#include <hip/hip_runtime.h>

// LeakyZOPlainOnce: 32-step LIF scan with LocalZO straight-through surrogate.
// inputs:  d_in[0] = x  (T*B*F fp32), d_in[1] = z (same shape)
// output:  d_out    = spikes (T*B*F fp32)
//
// R6 = R5 with PLAIN stores (the only change). A/B isolating nontemporal
// stores: R2 (nt, +24us) and R5 (nt, +21us) both regressed vs R0 (plain,
// 112us), and nt did NOT reduce FETCH_SIZE (MALL is memory-side; writes
// are absorbed there regardless). Mechanism for the regression: nt skips
// L2 write-combining -> slow store acks; vmcnt retires IN ORDER, so every
// later load wait also waits on the store ack.
//
// Structure rationale (unchanged):
//  - T as template param + FULL unroll -> ring indices are literals ->
//    SROA keeps ring buffers in VGPRs (R3's partial unroll demoted them to
//    LDS+scratch: 5M bank conflicts, doubled WRITE_SIZE).
//  - VEC=4 (R2 showed VEC=2's 2x instruction overhead beats its occupancy
//    gain), 3-deep prefetch: 6 KB loads in flight per wave, ~96 KB/CU.
//
// Determinism: spike = (h - surr*v) + surr*v is NOT exactly h when
// surr*v > 2; the residual feeds the u recurrence, so fp32 op order must
// match numpy exactly: separate mul+add with fp contract OFF inside
// lif_step (R2's absmax 4.5e-7 was FMA contraction sneaking into the
// inlined callee), true IEEE division by 0.1f, strict comparisons.

constexpr int BATCH = 128;
constexpr int FDIM  = 8192;
constexpr int STEP  = BATCH * FDIM;   // elements per time step = 1,048,576
constexpr int VEC   = 4;              // floats per thread per step
constexpr int PFD   = 3;              // prefetch distance (ring of 4)

typedef float f32x4 __attribute__((ext_vector_type(4)));

__device__ __forceinline__ float lif_step(float& u, float xs, float zs)
{
#pragma clang fp contract(off)
    float uu = 0.5f * u;          // beta * u   (separate mul + add)
    uu = uu + xs;
    float v = uu - 1.0f;          // u - u_th
    float az   = fabsf(zs);
    float ind  = (fabsf(v) < 0.05f * az) ? 1.0f : 0.0f;
    float surr = (az / 0.1f) * ind;
    float h    = (v > 0.0f) ? 1.0f : 0.0f;
    float a     = surr * v;
    float spike = (h - a) + a;    // straight-through forward
    u = uu - spike * 1.0f;        // soft reset
    return spike;
}

template <int T>
__global__ __launch_bounds__(256) void lif_zo_fixed(
    const float* __restrict__ x,
    const float* __restrict__ z,
    float* __restrict__ out)
{
#pragma clang fp contract(off)
    const int tid = blockIdx.x * blockDim.x + threadIdx.x;
    const long base = (long)tid * VEC;

    float u[VEC] = {0.0f, 0.0f, 0.0f, 0.0f};
    f32x4 xb[PFD + 1], zb[PFD + 1];

    // preload t = 0..PFD-1 (T > PFD for all uses of this template)
#pragma unroll
    for (int k = 0; k < PFD; ++k) {
        const long a = base + (long)k * STEP;
        xb[k] = *reinterpret_cast<const f32x4*>(x + a);
        zb[k] = *reinterpret_cast<const f32x4*>(z + a);
    }

#pragma unroll
    for (int t = 0; t < T; ++t) {
        if (t + PFD < T) {   // compile-time under full unroll
            const long p = base + (long)(t + PFD) * STEP;
            xb[(t + PFD) & 3] = *reinterpret_cast<const f32x4*>(x + p);
            zb[(t + PFD) & 3] = *reinterpret_cast<const f32x4*>(z + p);
        }
        const f32x4 xt = xb[t & 3];
        const f32x4 zt = zb[t & 3];
        f32x4 s;
        s.x = lif_step(u[0], xt.x, zt.x);
        s.y = lif_step(u[1], xt.y, zt.y);
        s.z = lif_step(u[2], xt.z, zt.z);
        s.w = lif_step(u[3], xt.w, zt.w);
        *reinterpret_cast<f32x4*>(out + base + (long)t * STEP) = s;
    }
}

// Generic-T fallback (R0 structure: proven correct, no arrays).
__global__ __launch_bounds__(256) void lif_zo_generic(
    const float* __restrict__ x,
    const float* __restrict__ z,
    float* __restrict__ out,
    int T)
{
#pragma clang fp contract(off)
    const int tid = blockIdx.x * blockDim.x + threadIdx.x;
    long idx = (long)tid * VEC;
    float u[VEC] = {0.0f, 0.0f, 0.0f, 0.0f};
    for (int t = 0; t < T; ++t, idx += STEP) {
        const f32x4 xt = *reinterpret_cast<const f32x4*>(x + idx);
        const f32x4 zt = *reinterpret_cast<const f32x4*>(z + idx);
        f32x4 s;
        s.x = lif_step(u[0], xt.x, zt.x);
        s.y = lif_step(u[1], xt.y, zt.y);
        s.z = lif_step(u[2], xt.z, zt.z);
        s.w = lif_step(u[3], xt.w, zt.w);
        *reinterpret_cast<f32x4*>(out + idx) = s;
    }
}

extern "C" void kernel_launch(void* const* d_in, const int* in_sizes, int n_in,
                              void* d_out, int out_size, void* d_ws, size_t ws_size,
                              hipStream_t stream)
{
    const float* x = (const float*)d_in[0];
    const float* z = (const float*)d_in[1];
    float* out = (float*)d_out;

    const int total = in_sizes[0];          // T * B * F
    const int T = total / STEP;             // = 32 for this problem

    const int nthreads = STEP / VEC;        // 262,144
    const int block = 256;
    const int grid = nthreads / block;      // 1024

    if (T == 32) {
        lif_zo_fixed<32><<<grid, block, 0, stream>>>(x, z, out);
    } else {
        lif_zo_generic<<<grid, block, 0, stream>>>(x, z, out, T);
    }
}